// Round 1
// baseline (2641.178 us; speedup 1.0000x reference)
//
#include <hip/hip_runtime.h>

typedef _Float16 f16;
typedef _Float16 h2 __attribute__((ext_vector_type(2)));
typedef unsigned int u32;

#define TB  256
#define TTT 2000
#define INW 42
#define HV  24
#define HN  48
#define HD  96
#define NTH 640

__device__ __forceinline__ float fsigm(float v) {
    return __builtin_amdgcn_rcpf(1.0f + __builtin_amdgcn_exp2f(-1.44269504089f * v));
}
__device__ __forceinline__ float ftanh(float v) {
    float e = __builtin_amdgcn_exp2f(2.88539008178f * v);
    return 1.0f - 2.0f * __builtin_amdgcn_rcpf(e + 1.0f);
}
__device__ __forceinline__ float dot2f(u32 a, u32 w, float c) {
#if __has_builtin(__builtin_amdgcn_fdot2)
    return __builtin_amdgcn_fdot2(__builtin_bit_cast(h2, a), __builtin_bit_cast(h2, w), c, false);
#else
    h2 av = __builtin_bit_cast(h2, a), wv = __builtin_bit_cast(h2, w);
    return c + (float)av[0] * (float)wv[0] + (float)av[1] * (float)wv[1];
#endif
}
__device__ __forceinline__ u32 packw(float a, float b) {
    h2 v; v[0] = (f16)a; v[1] = (f16)b;
    return __builtin_bit_cast(u32, v);
}

// raw barrier: flush LDS writes, do NOT drain vmcnt (keeps x prefetch in flight)
#define SYNCB() asm volatile("s_waitcnt lgkmcnt(0)\n\ts_barrier" ::: "memory")

#define ACC3(AV, W, IDX) do { u32 _a = (AV); \
    ar = dot2f(_a, W[0][IDX], ar); az = dot2f(_a, W[1][IDX], az); an = dot2f(_a, W[2][IDX], an); } while (0)
#define ACC3H(AV, W, IDX) do { u32 _a = (AV); \
    hr = dot2f(_a, W[0][IDX], hr); hz = dot2f(_a, W[1][IDX], hz); hn = dot2f(_a, W[2][IDX], hn); } while (0)
#define RED6(M) do { \
    ar += __shfl_xor(ar, M); az += __shfl_xor(az, M); an += __shfl_xor(an, M); \
    hr += __shfl_xor(hr, M); hz += __shfl_xor(hz, M); hn += __shfl_xor(hn, M); } while (0)

template<int N> struct IC { static constexpr int val = N; };

__global__ __launch_bounds__(NTH, 3) void rnnoise_kernel(
    const float* __restrict__ gx,
    const float* __restrict__ in_w,      const float* __restrict__ in_b,
    const float* __restrict__ vad_wih,   const float* __restrict__ vad_whh,
    const float* __restrict__ vad_bih,   const float* __restrict__ vad_bhh,
    const float* __restrict__ vad_out_w, const float* __restrict__ vad_out_b,
    const float* __restrict__ noise_wih, const float* __restrict__ noise_whh,
    const float* __restrict__ noise_bih, const float* __restrict__ noise_bhh,
    const float* __restrict__ den_wih,   const float* __restrict__ den_whh,
    const float* __restrict__ den_bih,   const float* __restrict__ den_bhh,
    const float* __restrict__ out_w,     const float* __restrict__ out_b,
    float* __restrict__ gains, float* __restrict__ vout)
{
    // activations, f16, double-buffered by timestep parity. x padded 42->48.
    __shared__ __align__(16) f16 s_x[2][48];
    __shared__ __align__(16) f16 s_tmp[2][24];
    __shared__ __align__(16) f16 s_vadh[2][24];
    __shared__ __align__(16) f16 s_noih[2][48];
    __shared__ __align__(16) f16 s_denh[2][96];

    const int tid = threadIdx.x;
    const int wid = tid >> 6;
    const int b   = blockIdx.x;

    if (tid < 96)  ((f16*)s_x)[tid]    = (f16)0.f;
    if (tid < 48)  ((f16*)s_tmp)[tid]  = (f16)0.f;
    if (tid < 48)  ((f16*)s_vadh)[tid] = (f16)0.f;
    if (tid < 96)  ((f16*)s_noih)[tid] = (f16)0.f;
    if (tid < 192) ((f16*)s_denh)[tid] = (f16)0.f;
    __syncthreads();  // PB1

    if (wid < 6) {
        // ================== DEN: 96 units x 4-lane teams ==================
        const int u = tid >> 2, q = tid & 3;
        u32 wdh[3][12], wdx[3][6], wdv[3][3], wdn[3][6];
        #pragma unroll
        for (int g = 0; g < 3; ++g) {
            const float* wr = den_whh + (g * HD + u) * HD + 24 * q;
            #pragma unroll
            for (int j = 0; j < 12; ++j) wdh[g][j] = packw(wr[2*j], wr[2*j+1]);
            const float* wi = den_wih + (g * HD + u) * 114;   // cols: [0,24)=vad [24,72)=noi [72,114)=x
            #pragma unroll
            for (int j = 0; j < 6; ++j) {
                int c0 = 12*q + 2*j;
                float a = (c0     < INW) ? wi[72 + c0]     : 0.f;
                float c = (c0 + 1 < INW) ? wi[72 + c0 + 1] : 0.f;
                wdx[g][j] = packw(a, c);
            }
            #pragma unroll
            for (int j = 0; j < 3; ++j) wdv[g][j] = packw(wi[6*q + 2*j], wi[6*q + 2*j + 1]);
            #pragma unroll
            for (int j = 0; j < 6; ++j) wdn[g][j] = packw(wi[24 + 12*q + 2*j], wi[24 + 12*q + 2*j + 1]);
        }
        const float bdr  = den_bih[u]      + den_bhh[u];
        const float bdz  = den_bih[HD+u]   + den_bhh[HD+u];
        const float bdni = den_bih[2*HD+u];
        const float bdnh = den_bhh[2*HD+u];
        __syncthreads();  // PB2
        __syncthreads();  // PB3

        auto step = [&](auto PC) {
            constexpr int P = decltype(PC)::val;
            float ar=0, az=0, an=0, hr=0, hz=0, hn=0;
            {   // P0: hh + x cols
                const uint4* hp = (const uint4*)&s_denh[P^1][24*q];
                #pragma unroll
                for (int v = 0; v < 3; ++v) {
                    uint4 a = hp[v];
                    ACC3H(a.x, wdh, 4*v+0); ACC3H(a.y, wdh, 4*v+1);
                    ACC3H(a.z, wdh, 4*v+2); ACC3H(a.w, wdh, 4*v+3);
                }
                const uint2* xp = (const uint2*)&s_x[P][12*q];
                #pragma unroll
                for (int v = 0; v < 3; ++v) {
                    uint2 a = xp[v];
                    ACC3(a.x, wdx, 2*v+0); ACC3(a.y, wdx, 2*v+1);
                }
            }
            SYNCB();  // B1: vad_h(t) ready
            {   const u32* vp = (const u32*)&s_vadh[P][6*q];
                #pragma unroll
                for (int v = 0; v < 3; ++v) ACC3(vp[v], wdv, v);
            }
            SYNCB();  // B2: noise_h(t) ready
            {   const uint2* np = (const uint2*)&s_noih[P][12*q];
                #pragma unroll
                for (int v = 0; v < 3; ++v) {
                    uint2 a = np[v];
                    ACC3(a.x, wdn, 2*v+0); ACC3(a.y, wdn, 2*v+1);
                }
            }
            RED6(1); RED6(2);
            if (q == 0) {
                float r = fsigm(ar + hr + bdr);
                float z = fsigm(az + hz + bdz);
                float n = ftanh(an + bdni + r * (hn + bdnh));
                float hp_ = (float)s_denh[P^1][u];
                s_denh[P][u] = (f16)(z * (hp_ - n) + n);
            }
            SYNCB();  // B3
        };
        #pragma clang loop unroll(disable)
        for (int t = 0; t < TTT; t += 2) { step(IC<0>{}); step(IC<1>{}); }

    } else if (wid < 9) {
        // ============ NOISE: 48 units x 4-lane teams (+ OUT proj t-1) ============
        const int L = tid - 384, u = L >> 2, q = L & 3;
        const int o = L >> 3, s8 = L & 7;
        const int oc = (o < 22) ? o : 0;
        u32 wnh[3][6], wnt[3][3], wnv[3][3], wnx[3][6], wo[6];
        #pragma unroll
        for (int g = 0; g < 3; ++g) {
            const float* wr = noise_whh + (g * HN + u) * HN + 12 * q;
            #pragma unroll
            for (int j = 0; j < 6; ++j) wnh[g][j] = packw(wr[2*j], wr[2*j+1]);
            const float* wi = noise_wih + (g * HN + u) * 90;  // cols: [0,24)=tmp [24,48)=vad [48,90)=x
            #pragma unroll
            for (int j = 0; j < 3; ++j) wnt[g][j] = packw(wi[6*q + 2*j], wi[6*q + 2*j + 1]);
            #pragma unroll
            for (int j = 0; j < 3; ++j) wnv[g][j] = packw(wi[24 + 6*q + 2*j], wi[24 + 6*q + 2*j + 1]);
            #pragma unroll
            for (int j = 0; j < 6; ++j) {
                int c0 = 12*q + 2*j;
                float a = (c0     < INW) ? wi[48 + c0]     : 0.f;
                float c = (c0 + 1 < INW) ? wi[48 + c0 + 1] : 0.f;
                wnx[g][j] = packw(a, c);
            }
        }
        #pragma unroll
        for (int j = 0; j < 6; ++j) wo[j] = packw(out_w[oc*HD + 12*s8 + 2*j], out_w[oc*HD + 12*s8 + 2*j + 1]);
        const float bnr  = noise_bih[u]    + noise_bhh[u];
        const float bnz  = noise_bih[HN+u] + noise_bhh[HN+u];
        const float bnni = noise_bih[2*HN+u];
        const float bnnh = noise_bhh[2*HN+u];
        const float bo   = out_b[oc];
        __syncthreads();  // PB2
        __syncthreads();  // PB3

        auto step = [&](auto PC, int t) {
            constexpr int P = decltype(PC)::val;
            if (t > 0) {  // OUT for step t-1 over den_h(t-1) = s_denh[P^1]
                float acc = 0;
                const uint2* dp = (const uint2*)&s_denh[P^1][12*s8];
                #pragma unroll
                for (int v = 0; v < 3; ++v) {
                    uint2 a = dp[v];
                    acc = dot2f(a.x, wo[2*v], acc); acc = dot2f(a.y, wo[2*v+1], acc);
                }
                acc += __shfl_xor(acc, 1); acc += __shfl_xor(acc, 2); acc += __shfl_xor(acc, 4);
                if (s8 == 0 && o < 22)
                    gains[((size_t)b * TTT + (t - 1)) * 22 + o] = fsigm(acc + bo);
            }
            float ar=0, az=0, an=0, hr=0, hz=0, hn=0;
            {   const uint2* hp = (const uint2*)&s_noih[P^1][12*q];
                #pragma unroll
                for (int v = 0; v < 3; ++v) { uint2 a = hp[v]; ACC3H(a.x, wnh, 2*v); ACC3H(a.y, wnh, 2*v+1); }
                const u32* tp = (const u32*)&s_tmp[P][6*q];
                #pragma unroll
                for (int v = 0; v < 3; ++v) ACC3(tp[v], wnt, v);
                const uint2* xp = (const uint2*)&s_x[P][12*q];
                #pragma unroll
                for (int v = 0; v < 3; ++v) { uint2 a = xp[v]; ACC3(a.x, wnx, 2*v); ACC3(a.y, wnx, 2*v+1); }
            }
            SYNCB();  // B1
            {   const u32* vp = (const u32*)&s_vadh[P][6*q];
                #pragma unroll
                for (int v = 0; v < 3; ++v) ACC3(vp[v], wnv, v);
            }
            RED6(1); RED6(2);
            if (q == 0) {
                float r = fsigm(ar + hr + bnr);
                float z = fsigm(az + hz + bnz);
                float n = ftanh(an + bnni + r * (hn + bnnh));
                float hp_ = (float)s_noih[P^1][u];
                s_noih[P][u] = (f16)(z * (hp_ - n) + n);
            }
            SYNCB();  // B2
            SYNCB();  // B3
        };
        #pragma clang loop unroll(disable)
        for (int t = 0; t < TTT; t += 2) { step(IC<0>{}, t); step(IC<1>{}, t + 1); }
        {   // tail: OUT for t = TTT-1 over s_denh[1]
            float acc = 0;
            const uint2* dp = (const uint2*)&s_denh[1][12*s8];
            #pragma unroll
            for (int v = 0; v < 3; ++v) {
                uint2 a = dp[v];
                acc = dot2f(a.x, wo[2*v], acc); acc = dot2f(a.y, wo[2*v+1], acc);
            }
            acc += __shfl_xor(acc, 1); acc += __shfl_xor(acc, 2); acc += __shfl_xor(acc, 4);
            if (s8 == 0 && o < 22)
                gains[((size_t)b * TTT + (TTT - 1)) * 22 + o] = fsigm(acc + bo);
        }

    } else {
        // ====== VAD wave: vad GRU (24 units x 2 lanes) + vad_out + tmp(t+1) + x prefetch ======
        const int l = tid - 576;
        const int u = (l < 48) ? (l >> 1) : 0, q = l & 1;
        u32 wvi[3][6], wvh[3][6], wtm[12], wvo[12];
        float bvr=0, bvz=0, bvni=0, bvnh=0, btm=0;
        if (l < 48) {
            #pragma unroll
            for (int g = 0; g < 3; ++g) {
                const float* wi = vad_wih + (g * HV + u) * HV + 12 * q;
                const float* wh = vad_whh + (g * HV + u) * HV + 12 * q;
                #pragma unroll
                for (int j = 0; j < 6; ++j) {
                    wvi[g][j] = packw(wi[2*j], wi[2*j+1]);
                    wvh[g][j] = packw(wh[2*j], wh[2*j+1]);
                }
            }
            #pragma unroll
            for (int j = 0; j < 12; ++j) {
                int c0 = 24*q + 2*j;
                float a = (c0     < INW) ? in_w[u*INW + c0]     : 0.f;
                float c = (c0 + 1 < INW) ? in_w[u*INW + c0 + 1] : 0.f;
                wtm[j] = packw(a, c);
            }
            bvr  = vad_bih[u]      + vad_bhh[u];
            bvz  = vad_bih[HV+u]   + vad_bhh[HV+u];
            bvni = vad_bih[2*HV+u];
            bvnh = vad_bhh[2*HV+u];
            btm  = in_b[u];
        }
        #pragma unroll
        for (int j = 0; j < 12; ++j) wvo[j] = packw(vad_out_w[2*j], vad_out_w[2*j+1]);
        const float bvo = vad_out_b[0];

        // prologue: x(0) -> s_x[0], tmp(0) -> s_tmp[0]
        float x0v = 0;
        if (l < INW) x0v = gx[((size_t)b * TTT + 0) * INW + l];
        if (l < INW) s_x[0][l] = (f16)x0v;
        __syncthreads();  // PB2
        if (l < 48) {
            const uint4* xp = (const uint4*)&s_x[0][24*q];
            float acc = 0;
            #pragma unroll
            for (int v = 0; v < 3; ++v) {
                uint4 a = xp[v];
                acc = dot2f(a.x, wtm[4*v+0], acc); acc = dot2f(a.y, wtm[4*v+1], acc);
                acc = dot2f(a.z, wtm[4*v+2], acc); acc = dot2f(a.w, wtm[4*v+3], acc);
            }
            acc += __shfl_xor(acc, 1);
            if (q == 0) s_tmp[0][u] = (f16)ftanh(acc + btm);
        }
        __syncthreads();  // PB3

        float xa = 0, xb = 0;
        if (l < INW) xb = gx[((size_t)b * TTT + 1) * INW + l];  // prefetch x(1)

        auto step = [&](auto PC, int t) {
            constexpr int P = decltype(PC)::val;
            // issue x(t+2) prefetch (consumed 1.5 steps later; raw barriers don't drain vmcnt)
            if (t + 2 < TTT && l < INW) {
                if constexpr (P == 0) xa = gx[((size_t)b * TTT + t + 2) * INW + l];
                else                  xb = gx[((size_t)b * TTT + t + 2) * INW + l];
            }
            float ar=0, az=0, an=0, hr=0, hz=0, hn=0;
            if (l < 48) {
                const uint2* tp = (const uint2*)&s_tmp[P][12*q];
                const uint2* hp = (const uint2*)&s_vadh[P^1][12*q];
                #pragma unroll
                for (int v = 0; v < 3; ++v) {
                    uint2 a = tp[v]; ACC3(a.x, wvi, 2*v); ACC3(a.y, wvi, 2*v+1);
                    uint2 h = hp[v]; ACC3H(h.x, wvh, 2*v); ACC3H(h.y, wvh, 2*v+1);
                }
                RED6(1);
                if (q == 0) {
                    float r = fsigm(ar + hr + bvr);
                    float z = fsigm(az + hz + bvz);
                    float n = ftanh(an + bvni + r * (hn + bvnh));
                    float hp_ = (float)s_vadh[P^1][u];
                    s_vadh[P][u] = (f16)(z * (hp_ - n) + n);
                }
            }
            SYNCB();  // B1
            if (l == 0) {
                float acc = 0;
                const uint4* vp = (const uint4*)&s_vadh[P][0];
                #pragma unroll
                for (int v = 0; v < 3; ++v) {
                    uint4 a = vp[v];
                    acc = dot2f(a.x, wvo[4*v+0], acc); acc = dot2f(a.y, wvo[4*v+1], acc);
                    acc = dot2f(a.z, wvo[4*v+2], acc); acc = dot2f(a.w, wvo[4*v+3], acc);
                }
                vout[(size_t)b * TTT + t] = fsigm(acc + bvo);
            }
            if (t + 1 < TTT && l < INW) {  // store x(t+1) f16 into parity P^1
                if constexpr (P == 0) s_x[1][l] = (f16)xb;
                else                  s_x[0][l] = (f16)xa;
            }
            SYNCB();  // B2 (x(t+1) now visible; read it for tmp(t+1))
            if (t + 1 < TTT && l < 48) {
                const uint4* xp = (const uint4*)&s_x[P^1][24*q];
                float acc = 0;
                #pragma unroll
                for (int v = 0; v < 3; ++v) {
                    uint4 a = xp[v];
                    acc = dot2f(a.x, wtm[4*v+0], acc); acc = dot2f(a.y, wtm[4*v+1], acc);
                    acc = dot2f(a.z, wtm[4*v+2], acc); acc = dot2f(a.w, wtm[4*v+3], acc);
                }
                acc += __shfl_xor(acc, 1);
                if (q == 0) s_tmp[P^1][u] = (f16)ftanh(acc + btm);
            }
            SYNCB();  // B3
        };
        #pragma clang loop unroll(disable)
        for (int t = 0; t < TTT; t += 2) { step(IC<0>{}, t); step(IC<1>{}, t + 1); }
    }
}

extern "C" void kernel_launch(void* const* d_in, const int* in_sizes, int n_in,
                              void* d_out, int out_size, void* d_ws, size_t ws_size,
                              hipStream_t stream) {
    (void)in_sizes; (void)n_in; (void)d_ws; (void)ws_size; (void)out_size;
    const float* gx        = (const float*)d_in[0];
    const float* in_w      = (const float*)d_in[1];
    const float* in_b      = (const float*)d_in[2];
    const float* vad_wih   = (const float*)d_in[3];
    const float* vad_whh   = (const float*)d_in[4];
    const float* vad_bih   = (const float*)d_in[5];
    const float* vad_bhh   = (const float*)d_in[6];
    const float* vad_out_w = (const float*)d_in[7];
    const float* vad_out_b = (const float*)d_in[8];
    const float* noise_wih = (const float*)d_in[9];
    const float* noise_whh = (const float*)d_in[10];
    const float* noise_bih = (const float*)d_in[11];
    const float* noise_bhh = (const float*)d_in[12];
    const float* den_wih   = (const float*)d_in[13];
    const float* den_whh   = (const float*)d_in[14];
    const float* den_bih   = (const float*)d_in[15];
    const float* den_bhh   = (const float*)d_in[16];
    const float* out_w     = (const float*)d_in[17];
    const float* out_b     = (const float*)d_in[18];
    float* gains = (float*)d_out;
    float* vout  = (float*)d_out + (size_t)TB * (size_t)TTT * 22;

    rnnoise_kernel<<<dim3(TB), dim3(NTH), 0, stream>>>(
        gx, in_w, in_b, vad_wih, vad_whh, vad_bih, vad_bhh, vad_out_w, vad_out_b,
        noise_wih, noise_whh, noise_bih, noise_bhh, den_wih, den_whh, den_bih, den_bhh,
        out_w, out_b, gains, vout);
}

// Round 3
// 1923.277 us; speedup vs baseline: 1.3733x; 1.3733x over previous
//
#include <hip/hip_runtime.h>

typedef _Float16 f16;
typedef _Float16 h2 __attribute__((ext_vector_type(2)));
typedef unsigned int u32;

#define TB  256
#define TTT 2000
#define INW 42
#define HV  24
#define HN  48
#define HD  96
#define NTH 640

__device__ __forceinline__ float fsigm(float v) {
    return __builtin_amdgcn_rcpf(1.0f + __builtin_amdgcn_exp2f(-1.44269504089f * v));
}
__device__ __forceinline__ float ftanh(float v) {
    float e = __builtin_amdgcn_exp2f(2.88539008178f * v);
    return 1.0f - 2.0f * __builtin_amdgcn_rcpf(e + 1.0f);
}
__device__ __forceinline__ float dot2f(u32 a, u32 w, float c) {
#if __has_builtin(__builtin_amdgcn_fdot2)
    return __builtin_amdgcn_fdot2(__builtin_bit_cast(h2, a), __builtin_bit_cast(h2, w), c, false);
#else
    h2 av = __builtin_bit_cast(h2, a), wv = __builtin_bit_cast(h2, w);
    return c + (float)av[0] * (float)wv[0] + (float)av[1] * (float)wv[1];
#endif
}
__device__ __forceinline__ u32 packw(float a, float b) {
    h2 v; v[0] = (f16)a; v[1] = (f16)b;
    return __builtin_bit_cast(u32, v);
}
// DPP quad-perm adds (xor patterns only — direction-free involutions).
// quad_perm xor1 = 0xB1, xor2 = 0x4E.
template<int CTRL>
__device__ __forceinline__ float dpp_add(float x) {
    int y = __builtin_amdgcn_mov_dpp(__builtin_bit_cast(int, x), CTRL, 0xF, 0xF, true);
    return x + __builtin_bit_cast(float, y);
}

// raw barrier: flush LDS ops, do NOT drain vmcnt (keeps x prefetch + out stores in flight)
#define SYNCB() asm volatile("s_waitcnt lgkmcnt(0)\n\ts_barrier" ::: "memory")

// accumulate input-side (rr,zz,an) / hidden-side (rr,zz,hn); r,z combined pre-reduce
#define ACCI(AV, W, IDX) do { u32 _a = (AV); \
    rr = dot2f(_a, W[0][IDX], rr); zz = dot2f(_a, W[1][IDX], zz); an = dot2f(_a, W[2][IDX], an); } while (0)
#define ACCH(AV, W, IDX) do { u32 _a = (AV); \
    rr = dot2f(_a, W[0][IDX], rr); zz = dot2f(_a, W[1][IDX], zz); hn = dot2f(_a, W[2][IDX], hn); } while (0)
#define RED4_Q() do { \
    rr = dpp_add<0xB1>(rr); rr = dpp_add<0x4E>(rr); \
    zz = dpp_add<0xB1>(zz); zz = dpp_add<0x4E>(zz); \
    an = dpp_add<0xB1>(an); an = dpp_add<0x4E>(an); \
    hn = dpp_add<0xB1>(hn); hn = dpp_add<0x4E>(hn); } while (0)
#define RED4_1() do { \
    rr = dpp_add<0xB1>(rr); zz = dpp_add<0xB1>(zz); \
    an = dpp_add<0xB1>(an); hn = dpp_add<0xB1>(hn); } while (0)

template<int N> struct IC { static constexpr int val = N; };

__global__ __launch_bounds__(NTH, 3) void rnnoise_kernel(
    const float* __restrict__ gx,
    const float* __restrict__ in_w,      const float* __restrict__ in_b,
    const float* __restrict__ vad_wih,   const float* __restrict__ vad_whh,
    const float* __restrict__ vad_bih,   const float* __restrict__ vad_bhh,
    const float* __restrict__ vad_out_w, const float* __restrict__ vad_out_b,
    const float* __restrict__ noise_wih, const float* __restrict__ noise_whh,
    const float* __restrict__ noise_bih, const float* __restrict__ noise_bhh,
    const float* __restrict__ den_wih,   const float* __restrict__ den_whh,
    const float* __restrict__ den_bih,   const float* __restrict__ den_bhh,
    const float* __restrict__ out_w,     const float* __restrict__ out_b,
    float* __restrict__ gains, float* __restrict__ vout)
{
    // depth-4 ring buffers, slot = timestep & 3
    __shared__ __align__(16) f16 s_x[4][48];
    __shared__ __align__(16) f16 s_tmp[4][24];
    __shared__ __align__(16) f16 s_vadh[4][24];
    __shared__ __align__(16) f16 s_noih[4][48];
    __shared__ __align__(16) f16 s_denh[4][96];

    const int tid  = threadIdx.x;
    const int wid  = tid >> 6;
    const int lane = tid & 63;
    const int b    = blockIdx.x;

    if (tid < 96)  ((u32*)s_x)[tid]    = 0u;
    if (tid < 48)  ((u32*)s_tmp)[tid]  = 0u;
    if (tid < 48)  ((u32*)s_vadh)[tid] = 0u;
    if (tid < 96)  ((u32*)s_noih)[tid] = 0u;
    if (tid < 192) ((u32*)s_denh)[tid] = 0u;
    __syncthreads();

    // role map (assuming wid%4 SIMD round-robin): den pairs on SIMD2/3,
    // {den,noi,noi} on SIMD0, {den,noi,vad} on SIMD1.
    const int role = (wid == 9) ? 2 : ((wid == 4 || wid == 5 || wid == 8) ? 1 : 0);

    if (role == 0) {
        // ================== DEN: computes t = k-3 at tick k ==================
        const int dwi = (wid < 4) ? wid : (wid - 2);       // 0..5
        const int u = dwi * 16 + (lane >> 2), q = lane & 3;
        u32 wdh[3][12], wdx[3][6], wdv[3][3], wdn[3][6];
        #pragma unroll
        for (int g = 0; g < 3; ++g) {
            const float* wr = den_whh + (g * HD + u) * HD + 24 * q;
            #pragma unroll
            for (int j = 0; j < 12; ++j) wdh[g][j] = packw(wr[2*j], wr[2*j+1]);
            const float* wi = den_wih + (g * HD + u) * 114;   // [0,24)=vad [24,72)=noi [72,114)=x
            #pragma unroll
            for (int j = 0; j < 6; ++j) {
                int c0 = 12*q + 2*j;
                float a = (c0     < INW) ? wi[72 + c0]     : 0.f;
                float c = (c0 + 1 < INW) ? wi[72 + c0 + 1] : 0.f;
                wdx[g][j] = packw(a, c);
            }
            #pragma unroll
            for (int j = 0; j < 3; ++j) wdv[g][j] = packw(wi[6*q + 2*j], wi[6*q + 2*j + 1]);
            #pragma unroll
            for (int j = 0; j < 6; ++j) wdn[g][j] = packw(wi[24 + 12*q + 2*j], wi[24 + 12*q + 2*j + 1]);
        }
        const float bdr  = den_bih[u]      + den_bhh[u];
        const float bdz  = den_bih[HD+u]   + den_bhh[HD+u];
        const float bdni = den_bih[2*HD+u];
        const float bdnh = den_bhh[2*HD+u];
        float hreg = 0.f;

        auto step = [&](auto PC, int k) {
            constexpr int P  = decltype(PC)::val;
            constexpr int SI = (P + 1) & 3;   // inputs at t=k-3; also write slot
            if (k >= 3 && k <= TTT + 2) {
                float rr = 0, zz = 0, an = 0, hn = 0;
                const uint4* hp = (const uint4*)&s_denh[P][24*q];   // den_h(t-1)
                #pragma unroll
                for (int v = 0; v < 3; ++v) {
                    uint4 a = hp[v];
                    ACCH(a.x, wdh, 4*v+0); ACCH(a.y, wdh, 4*v+1);
                    ACCH(a.z, wdh, 4*v+2); ACCH(a.w, wdh, 4*v+3);
                }
                const uint2* xp = (const uint2*)&s_x[SI][12*q];
                #pragma unroll
                for (int v = 0; v < 3; ++v) { uint2 a = xp[v]; ACCI(a.x, wdx, 2*v); ACCI(a.y, wdx, 2*v+1); }
                const u32* vp = (const u32*)&s_vadh[SI][6*q];
                #pragma unroll
                for (int v = 0; v < 3; ++v) ACCI(vp[v], wdv, v);
                const uint2* np = (const uint2*)&s_noih[SI][12*q];
                #pragma unroll
                for (int v = 0; v < 3; ++v) { uint2 a = np[v]; ACCI(a.x, wdn, 2*v); ACCI(a.y, wdn, 2*v+1); }
                RED4_Q();
                if (q == 0) {
                    float r = fsigm(rr + bdr);
                    float z = fsigm(zz + bdz);
                    float n = ftanh(an + bdni + r * (hn + bdnh));
                    hreg = z * (hreg - n) + n;
                    s_denh[SI][u] = (f16)hreg;
                }
            }
            SYNCB();
        };
        #pragma clang loop unroll(disable)
        for (int k0 = 0; k0 < TTT + 4; k0 += 4) {
            step(IC<0>{}, k0); step(IC<1>{}, k0+1); step(IC<2>{}, k0+2); step(IC<3>{}, k0+3);
        }

    } else if (role == 1) {
        // ====== NOISE: t = k-2 at tick k; OUT projection: t = k-4 ======
        const int nwi = (wid == 4) ? 0 : ((wid == 5) ? 1 : 2);
        const int L = nwi * 64 + lane, u = L >> 2, q = L & 3;
        const int o = L >> 3, s8 = L & 7;
        const int oc = (o < 22) ? o : 0;
        u32 wnh[3][6], wnt[3][3], wnv[3][3], wnx[3][6], wo[6];
        #pragma unroll
        for (int g = 0; g < 3; ++g) {
            const float* wr = noise_whh + (g * HN + u) * HN + 12 * q;
            #pragma unroll
            for (int j = 0; j < 6; ++j) wnh[g][j] = packw(wr[2*j], wr[2*j+1]);
            const float* wi = noise_wih + (g * HN + u) * 90;  // [0,24)=tmp [24,48)=vad [48,90)=x
            #pragma unroll
            for (int j = 0; j < 3; ++j) wnt[g][j] = packw(wi[6*q + 2*j], wi[6*q + 2*j + 1]);
            #pragma unroll
            for (int j = 0; j < 3; ++j) wnv[g][j] = packw(wi[24 + 6*q + 2*j], wi[24 + 6*q + 2*j + 1]);
            #pragma unroll
            for (int j = 0; j < 6; ++j) {
                int c0 = 12*q + 2*j;
                float a = (c0     < INW) ? wi[48 + c0]     : 0.f;
                float c = (c0 + 1 < INW) ? wi[48 + c0 + 1] : 0.f;
                wnx[g][j] = packw(a, c);
            }
        }
        #pragma unroll
        for (int j = 0; j < 6; ++j) wo[j] = packw(out_w[oc*HD + 12*s8 + 2*j], out_w[oc*HD + 12*s8 + 2*j + 1]);
        const float bnr  = noise_bih[u]    + noise_bhh[u];
        const float bnz  = noise_bih[HN+u] + noise_bhh[HN+u];
        const float bnni = noise_bih[2*HN+u];
        const float bnnh = noise_bhh[2*HN+u];
        const float bo   = out_b[oc];
        float hreg = 0.f;

        auto step = [&](auto PC, int k) {
            constexpr int P  = decltype(PC)::val;
            constexpr int SI = (P + 2) & 3;   // t = k-2 inputs + write
            constexpr int SH = (P + 1) & 3;   // noise_h(t-1)
            if (k >= 2 && k <= TTT + 1) {
                float rr = 0, zz = 0, an = 0, hn = 0;
                const uint2* hp = (const uint2*)&s_noih[SH][12*q];
                #pragma unroll
                for (int v = 0; v < 3; ++v) { uint2 a = hp[v]; ACCH(a.x, wnh, 2*v); ACCH(a.y, wnh, 2*v+1); }
                const u32* tp = (const u32*)&s_tmp[SI][6*q];
                #pragma unroll
                for (int v = 0; v < 3; ++v) ACCI(tp[v], wnt, v);
                const u32* vp = (const u32*)&s_vadh[SI][6*q];
                #pragma unroll
                for (int v = 0; v < 3; ++v) ACCI(vp[v], wnv, v);
                const uint2* xp = (const uint2*)&s_x[SI][12*q];
                #pragma unroll
                for (int v = 0; v < 3; ++v) { uint2 a = xp[v]; ACCI(a.x, wnx, 2*v); ACCI(a.y, wnx, 2*v+1); }
                RED4_Q();
                if (q == 0) {
                    float r = fsigm(rr + bnr);
                    float z = fsigm(zz + bnz);
                    float n = ftanh(an + bnni + r * (hn + bnnh));
                    hreg = z * (hreg - n) + n;
                    s_noih[SI][u] = (f16)hreg;
                }
            }
            if (k >= 4) {   // OUT: gains(t=k-4) over den_h(k-4) in slot P
                float acc = 0;
                const uint2* dp = (const uint2*)&s_denh[P][12*s8];
                #pragma unroll
                for (int v = 0; v < 3; ++v) {
                    uint2 a = dp[v];
                    acc = dot2f(a.x, wo[2*v], acc); acc = dot2f(a.y, wo[2*v+1], acc);
                }
                // quad-perm xor reduce within quads, then direction-free shfl for the
                // cross-quad step (row_ror:4 read the WRONG quad — lane i reads i-4, not i+4)
                acc = dpp_add<0xB1>(acc); acc = dpp_add<0x4E>(acc);
                acc += __shfl_xor(acc, 4);
                if (s8 == 0 && o < 22)
                    gains[((size_t)b * TTT + (k - 4)) * 22 + o] = fsigm(acc + bo);
            }
            SYNCB();
        };
        #pragma clang loop unroll(disable)
        for (int k0 = 0; k0 < TTT + 4; k0 += 4) {
            step(IC<0>{}, k0); step(IC<1>{}, k0+1); step(IC<2>{}, k0+2); step(IC<3>{}, k0+3);
        }

    } else {
        // ====== VAD wave: x stage + tmp(k) + vad GRU(t=k-1) + vad_out(t=k-1) ======
        const int l = lane;
        const int u = (l < 48) ? (l >> 1) : 0, q2 = l & 1;
        u32 wvi[3][6], wvh[3][6], wtm[12];
        float bvr = 0, bvz = 0, bvni = 0, bvnh = 0, btm = 0, wvo_u = 0;
        if (l < 48) {
            #pragma unroll
            for (int g = 0; g < 3; ++g) {
                const float* wi = vad_wih + (g * HV + u) * HV + 12 * q2;
                const float* wh = vad_whh + (g * HV + u) * HV + 12 * q2;
                #pragma unroll
                for (int j = 0; j < 6; ++j) {
                    wvi[g][j] = packw(wi[2*j], wi[2*j+1]);
                    wvh[g][j] = packw(wh[2*j], wh[2*j+1]);
                }
            }
            #pragma unroll
            for (int j = 0; j < 12; ++j) {
                int c0 = 24*q2 + 2*j;
                float a = (c0     < INW) ? in_w[u*INW + c0]     : 0.f;
                float c = (c0 + 1 < INW) ? in_w[u*INW + c0 + 1] : 0.f;
                wtm[j] = packw(a, c);
            }
            bvr  = vad_bih[u]      + vad_bhh[u];
            bvz  = vad_bih[HV+u]   + vad_bhh[HV+u];
            bvni = vad_bih[2*HV+u];
            bvnh = vad_bhh[2*HV+u];
            btm  = in_b[u];
            if (q2 == 0) wvo_u = vad_out_w[u];
        }
        const float bvo = vad_out_b[0];
        float hreg = 0.f;

        // prologue: prefetch x(0..3)
        float xa = 0, xb = 0, xc = 0, xd = 0;
        if (l < INW) {
            xa = gx[((size_t)b * TTT + 0) * INW + l];
            xb = gx[((size_t)b * TTT + 1) * INW + l];
            xc = gx[((size_t)b * TTT + 2) * INW + l];
            xd = gx[((size_t)b * TTT + 3) * INW + l];
        }

        auto step = [&](auto PC, int k) {
            constexpr int P  = decltype(PC)::val;
            constexpr int ST = (P + 3) & 3;   // tmp(k-1) read; vad_h(k-1) write
            constexpr int SH = (P + 2) & 3;   // vad_h(k-2)
            // stage x(k) into slot P, then refill the phase register with x(k+4)
            if (k < TTT && l < INW) {
                float xv;
                if constexpr (P == 0) xv = xa; else if constexpr (P == 1) xv = xb;
                else if constexpr (P == 2) xv = xc; else xv = xd;
                s_x[P][l] = (f16)xv;
            }
            if (k + 4 < TTT && l < INW) {
                float xv = gx[((size_t)b * TTT + (k + 4)) * INW + l];
                if constexpr (P == 0) xa = xv; else if constexpr (P == 1) xb = xv;
                else if constexpr (P == 2) xc = xv; else xd = xv;
            }
            // vad GRU for t = k-1
            if (k >= 1 && k <= TTT) {
                float rr = 0, zz = 0, an = 0, hn = 0;
                if (l < 48) {
                    const uint2* tp = (const uint2*)&s_tmp[ST][12*q2];
                    const uint2* hp = (const uint2*)&s_vadh[SH][12*q2];
                    #pragma unroll
                    for (int v = 0; v < 3; ++v) {
                        uint2 a = tp[v]; ACCI(a.x, wvi, 2*v); ACCI(a.y, wvi, 2*v+1);
                        uint2 h = hp[v]; ACCH(h.x, wvh, 2*v); ACCH(h.y, wvh, 2*v+1);
                    }
                    RED4_1();
                    if (q2 == 0) {
                        float r = fsigm(rr + bvr);
                        float z = fsigm(zz + bvz);
                        float n = ftanh(an + bvni + r * (hn + bvnh));
                        hreg = z * (hreg - n) + n;
                        s_vadh[ST][u] = (f16)hreg;
                    }
                }
                // vad_out(t) — full-wave reduce of w_u*h_u (q2==0 lanes contribute).
                // quad xor via DPP, all cross-quad steps via direction-free shfl_xor.
                float val = (l < 48 && q2 == 0) ? (wvo_u * hreg) : 0.f;
                val = dpp_add<0xB1>(val); val = dpp_add<0x4E>(val);
                val += __shfl_xor(val, 4); val += __shfl_xor(val, 8);
                val += __shfl_xor(val, 16); val += __shfl_xor(val, 32);
                if (l == 0) vout[(size_t)b * TTT + (k - 1)] = fsigm(val + bvo);
            }
            // tmp(k) from x(k) just staged (same-wave ds dependency, no barrier needed)
            if (k < TTT) {
                float acc = 0;
                if (l < 48) {
                    const uint4* xp = (const uint4*)&s_x[P][24*q2];
                    #pragma unroll
                    for (int v = 0; v < 3; ++v) {
                        uint4 a = xp[v];
                        acc = dot2f(a.x, wtm[4*v+0], acc); acc = dot2f(a.y, wtm[4*v+1], acc);
                        acc = dot2f(a.z, wtm[4*v+2], acc); acc = dot2f(a.w, wtm[4*v+3], acc);
                    }
                    acc = dpp_add<0xB1>(acc);
                    if (q2 == 0) s_tmp[P][u] = (f16)ftanh(acc + btm);
                }
            }
            SYNCB();
        };
        #pragma clang loop unroll(disable)
        for (int k0 = 0; k0 < TTT + 4; k0 += 4) {
            step(IC<0>{}, k0); step(IC<1>{}, k0+1); step(IC<2>{}, k0+2); step(IC<3>{}, k0+3);
        }
    }
}

extern "C" void kernel_launch(void* const* d_in, const int* in_sizes, int n_in,
                              void* d_out, int out_size, void* d_ws, size_t ws_size,
                              hipStream_t stream) {
    (void)in_sizes; (void)n_in; (void)d_ws; (void)ws_size; (void)out_size;
    const float* gx        = (const float*)d_in[0];
    const float* in_w      = (const float*)d_in[1];
    const float* in_b      = (const float*)d_in[2];
    const float* vad_wih   = (const float*)d_in[3];
    const float* vad_whh   = (const float*)d_in[4];
    const float* vad_bih   = (const float*)d_in[5];
    const float* vad_bhh   = (const float*)d_in[6];
    const float* vad_out_w = (const float*)d_in[7];
    const float* vad_out_b = (const float*)d_in[8];
    const float* noise_wih = (const float*)d_in[9];
    const float* noise_whh = (const float*)d_in[10];
    const float* noise_bih = (const float*)d_in[11];
    const float* noise_bhh = (const float*)d_in[12];
    const float* den_wih   = (const float*)d_in[13];
    const float* den_whh   = (const float*)d_in[14];
    const float* den_bih   = (const float*)d_in[15];
    const float* den_bhh   = (const float*)d_in[16];
    const float* out_w     = (const float*)d_in[17];
    const float* out_b     = (const float*)d_in[18];
    float* gains = (float*)d_out;
    float* vout  = (float*)d_out + (size_t)TB * (size_t)TTT * 22;

    rnnoise_kernel<<<dim3(TB), dim3(NTH), 0, stream>>>(
        gx, in_w, in_b, vad_wih, vad_whh, vad_bih, vad_bhh, vad_out_w, vad_out_b,
        noise_wih, noise_whh, noise_bih, noise_bhh, den_wih, den_whh, den_bih, den_bhh,
        out_w, out_b, gains, vout);
}